// Round 15
// baseline (575.056 us; speedup 1.0000x reference)
//
#include <hip/hip_runtime.h>
#include <math.h>

#define BB 256
#define LL 3
#define CC 8
#define VV 20
#define SS 32
#define DD 64
#define NG (BB * LL * CC)  // 6144 groups per segment
#define NE_ROWS 200001
#define PRE_GRID 2048  // 256 prologue blocks + 1792 conv blocks

typedef float v4f __attribute__((ext_vector_type(4)));
typedef _Float16 h4 __attribute__((ext_vector_type(4)));

__device__ __forceinline__ float sigmoidf_(float x) { return 1.0f / (1.0f + __expf(-x)); }
__device__ __forceinline__ float dot4v_(v4f a, v4f b) {
    return a[0] * b[0] + a[1] * b[1] + a[2] * b[2] + a[3] * b[3];
}

// ---------------- K1: fused {prologue (blocks 0..255)} || {fp32->fp16 conv (rest)} ------
__global__ __launch_bounds__(256) void pre_all(
    const float* __restrict__ E, const float* __restrict__ Rr, const int* __restrict__ ucv,
    const int* __restrict__ ucl, const int* __restrict__ items, const int* __restrict__ icl,
    const int* __restrict__ negs, const int* __restrict__ ncl, const float* __restrict__ W,
    const float* __restrict__ W_ht, const float* __restrict__ Wc, const float* __restrict__ Wv,
    float* __restrict__ wcce_u, float* __restrict__ whv_u, float* __restrict__ wcce_i,
    float* __restrict__ wcce_n, float* __restrict__ ie_i, float* __restrict__ ie_n,
    float* __restrict__ dots_r, _Float16* __restrict__ E16, int* __restrict__ cnt) {
    int tid = threadIdx.x;
    if (blockIdx.x >= BB) {
        // ---- conversion lane: stream E (51MB) -> E16 (25.6MB), grid-stride ----
        int n4 = (NE_ROWS * DD) / 4;
        int nconv = (PRE_GRID - BB) * 256;
        for (int i = (blockIdx.x - BB) * 256 + tid; i < n4; i += nconv) {
            v4f x = *(const v4f*)(E + (long)i * 4);
            h4 o;
            o[0] = (_Float16)x[0];
            o[1] = (_Float16)x[1];
            o[2] = (_Float16)x[2];
            o[3] = (_Float16)x[3];
            *(h4*)(E16 + (long)i * 4) = o;
        }
        return;
    }
    // ---- prologue lane: per-b block ----
    int b = blockIdx.x;
    if (tid == 0) cnt[b] = 0;  // re-zeroed every launch (deterministic under graph replay)
    int d = tid & 63, q = tid >> 6;  // q in 0..3
    __shared__ float vcs[CC][DD];
    __shared__ float part[4][DD];
    __shared__ float part2[4][DD];
    __shared__ float cce_u_s[DD], vce_u_s[DD], cce_i_s[DD], cce_n_s[DD], vmean_s[DD];
    __shared__ float ie_s[2][DD];
    __shared__ float smw[3][DD];  // wc_r halves: [0]=user, [1]=item, [2]=neg

    float p1 = 0.f;
    for (int cc = 0; cc < 2; ++cc) {
        int c = q + cc * 4;
        const int* iv = ucv + (b * CC + c) * VV;
        float a = 0.f;
#pragma unroll
        for (int v = 0; v < VV; ++v) a += E[(long)iv[v] * DD + d];
        vcs[c][d] = a;
        p1 += E[(long)ucl[b * CC + c] * DD + d];
    }
    part[q][d] = p1;
    __syncthreads();
    {
        float sacc = 0.f;
        for (int cc = 0; cc < 2; ++cc) {
            int c = q + cc * 4;
            float m = 0.f;
#pragma unroll 8
            for (int k = 0; k < DD; ++k) m += vcs[c][k] * Wc[k * DD + d];
            sacc += sigmoidf_(m);
        }
        part2[q][d] = sacc;
    }
    __syncthreads();
    if (q == 0) {
        float s = 0.f;
#pragma unroll
        for (int i = 0; i < 4; ++i) s += part[i][d] + part2[i][d];
        cce_u_s[d] = s * (1.f / CC);
        float vm = 0.f;
#pragma unroll
        for (int c = 0; c < CC; ++c) vm += vcs[c][d];
        vmean_s[d] = vm * (1.f / CC);
    }
    __syncthreads();
    {
        float m = 0.f;
        for (int k = q * 16; k < q * 16 + 16; ++k) m += vmean_s[k] * Wv[k * DD + d];
        part[q][d] = m;
    }
    {
        const int* cl = (q < 2) ? icl : ncl;
        int c0 = (q & 1) ? 5 : 1, c1 = (q & 1) ? 8 : 5;
        float m = 0.f;
        for (int c = c0; c < c1; ++c) m += E[(long)cl[b * CC + c] * DD + d];
        part2[q][d] = m;
        if (q == 1) ie_s[0][d] = E[(long)items[b] * DD + d];
        if (q == 3) ie_s[1][d] = E[(long)negs[b] * DD + d];
    }
    __syncthreads();
    if (q == 0) {
        vce_u_s[d] = sigmoidf_(part[0][d] + part[1][d] + part[2][d] + part[3][d]);
        float ie = ie_s[0][d];
        cce_i_s[d] = ie * (1.f + (part2[0][d] + part2[1][d]) * (1.f / 7.f));
        ie_i[b * DD + d] = ie;
    } else if (q == 1) {
        float ie = ie_s[1][d];
        cce_n_s[d] = ie * (1.f + (part2[2][d] + part2[3][d]) * (1.f / 7.f));
        ie_n[b * DD + d] = ie;
    }
    __syncthreads();
    // Phase E: 4 mat-vecs; capture wc_r halves (k>=64) into smem for phase F
    {
        int k = tid & 127, sel = tid >> 7;
        const float* wr = (sel ? W_ht : W) + k * DD;
        const float* wr2 = W + k * DD;
        const float* v1 = sel ? vce_u_s : cce_u_s;
        const float* v2 = sel ? cce_n_s : cce_i_s;
        float a = 0.f, c2 = 0.f;
#pragma unroll 8
        for (int kk = 0; kk < DD; ++kk) {
            a += wr[kk] * v1[kk];
            c2 += wr2[kk] * v2[kk];
        }
        if (sel == 0) {
            wcce_u[b * 128 + k] = a;
            wcce_i[b * 128 + k] = c2;
            if (k >= 64) {
                smw[0][k - 64] = a;
                smw[1][k - 64] = c2;
            }
        } else {
            whv_u[b * 128 + k] = a;
            wcce_n[b * 128 + k] = c2;
            if (k >= 64) smw[2][k - 64] = c2;
        }
    }
    __syncthreads();
    // Phase F: dots_r[seg][b][rel] = R[rel] . wc_r[seg]
    if (tid < 96) {
        int sg = tid >> 5, rel = tid & 31;
        const float* rr = Rr + rel * DD;
        float acc = 0.f;
#pragma unroll 8
        for (int k = 0; k < DD; ++k) acc += rr[k] * smw[sg][k];
        dots_r[(sg * BB + b) * 32 + rel] = acc;
    }
}

// ---------------- K2: layer_emb + tail-block postlude (no 3rd kernel) ------------------
// 1-wave blocks, fp16 trickle gathers (R13 structure, at the ~2.8 TB/s fetch wall).
// Last-arriving block per b (device-scope atomic + fences, guide G12/G16) runs the
// postlude for that b entirely in-wave (all reductions are 64-lane shuffles).
__global__ __launch_bounds__(64) void layer_all(
    const _Float16* __restrict__ E16, const int* __restrict__ uts, const int* __restrict__ its,
    const int* __restrict__ nts, const float* __restrict__ wcce_u,
    const float* __restrict__ whv_u, const float* __restrict__ wcce_i,
    const float* __restrict__ wcce_n, const float* __restrict__ dots_r,
    const float* __restrict__ ie_i, const float* __restrict__ ie_n, float* __restrict__ o_all,
    int* __restrict__ cnt, float* __restrict__ out) {
    int lane = threadIdx.x;
    int f = lane & 15, grp = lane >> 4;  // 16 f-lanes x 4 row-groups
    int gg = blockIdx.x;
    int seg = gg / NG;
    int g = gg - seg * NG;
    int b = g / (LL * CC);
    const int* ts = (seg == 0) ? uts : (seg == 1) ? its : nts;
    const float* wcp = (seg == 0) ? wcce_u : (seg == 1) ? wcce_i : wcce_n;
    const bool has_p2 = (seg == 0);
    const int* tg = ts + (long)g * 3 * SS;

    // coalesced index loads + broadcast
    int idx_a = tg[lane];              // h: lanes 0..31, r: lanes 32..63
    int idx_b = tg[64 + (lane & 31)];  // t
    int hix[8], rixl[8], tix[8];
#pragma unroll
    for (int p = 0; p < 8; ++p) {
        int row = p * 4 + grp;
        hix[p] = __shfl(idx_a, row, 64);
        rixl[p] = __shfl(idx_a, 32 + row, 64);
        tix[p] = __shfl(idx_b, row, 64);
    }
    const float* drb = dots_r + ((long)seg * BB + b) * 32;
    float rdot[8];
#pragma unroll
    for (int p = 0; p < 8; ++p) rdot[p] = drb[rixl[p]];
    v4f wch = ((const v4f*)(wcp + b * 128))[f];
    v4f whh = {0.f, 0.f, 0.f, 0.f}, wht = whh;
    if (has_p2) {
        whh = ((const v4f*)(whv_u + b * 128))[f];
        wht = ((const v4f*)(whv_u + b * 128))[16 + f];
    }
    // 16 fp16 row gathers (1 cache line per row)
    v4f hv[8], t4[8];
#pragma unroll
    for (int p = 0; p < 8; ++p) {
        h4 x = *(const h4*)(E16 + (long)hix[p] * DD + f * 4);
        hv[p] = (v4f){(float)x[0], (float)x[1], (float)x[2], (float)x[3]};
    }
#pragma unroll
    for (int p = 0; p < 8; ++p) {
        h4 x = *(const h4*)(E16 + (long)tix[p] * DD + f * 4);
        t4[p] = (v4f){(float)x[0], (float)x[1], (float)x[2], (float)x[3]};
    }

    float s1[8], s2[8];
#pragma unroll
    for (int p = 0; p < 8; ++p) {
        float a1 = dot4v_(hv[p], wch);
#pragma unroll
        for (int m = 1; m < 16; m <<= 1) a1 += __shfl_xor(a1, m, 64);
        s1[p] = a1 + rdot[p];
    }
    if (has_p2) {
#pragma unroll
        for (int p = 0; p < 8; ++p) {
            float a2 = dot4v_(hv[p], whh) + dot4v_(t4[p], wht);
#pragma unroll
            for (int m = 1; m < 16; m <<= 1) a2 += __shfl_xor(a2, m, 64);
            s2[p] = a2;
        }
    }
    float mx = -1e30f;
#pragma unroll
    for (int p = 0; p < 8; ++p) {
        s1[p] = sigmoidf_(s1[p]);
        mx = fmaxf(mx, s1[p]);
    }
    mx = fmaxf(mx, __shfl_xor(mx, 16, 64));
    mx = fmaxf(mx, __shfl_xor(mx, 32, 64));
    float se = 0.f;
#pragma unroll
    for (int p = 0; p < 8; ++p) {
        s1[p] = __expf(s1[p] - mx);
        se += s1[p];
    }
    se += __shfl_xor(se, 16, 64);
    se += __shfl_xor(se, 32, 64);
    float inv = 1.f / se;
    float4 oacc = make_float4(0.f, 0.f, 0.f, 0.f);
#pragma unroll
    for (int p = 0; p < 8; ++p) {
        float wgt = s1[p] * inv;
        if (has_p2) wgt *= sigmoidf_(s2[p]);
        oacc.x += wgt * t4[p][0];
        oacc.y += wgt * t4[p][1];
        oacc.z += wgt * t4[p][2];
        oacc.w += wgt * t4[p][3];
    }
#pragma unroll
    for (int m = 16; m <= 32; m <<= 1) {
        oacc.x += __shfl_xor(oacc.x, m, 64);
        oacc.y += __shfl_xor(oacc.y, m, 64);
        oacc.z += __shfl_xor(oacc.z, m, 64);
        oacc.w += __shfl_xor(oacc.w, m, 64);
    }
    float qq = oacc.x * oacc.x + oacc.y * oacc.y + oacc.z * oacc.z + oacc.w * oacc.w;
#pragma unroll
    for (int m = 1; m < 16; m <<= 1) qq += __shfl_xor(qq, m, 64);
    float innorm = 1.f / fmaxf(sqrtf(qq), 1e-12f);
    if (grp == 0) {
        oacc.x *= innorm;
        oacc.y *= innorm;
        oacc.z *= innorm;
        oacc.w *= innorm;
        *(float4*)(o_all + (long)gg * DD + f * 4) = oacc;
    }

    // ---- tail-block postlude: last of b's 72 groups finishes the batch row ----
    __threadfence();  // release: o_all row visible device-wide
    int prev = 0;
    if (lane == 0) prev = atomicAdd(&cnt[b], 1);
    prev = __shfl(prev, 0, 64);
    if (prev != 3 * LL * CC - 1) return;
    __threadfence();  // acquire: all other blocks' o_all rows visible

    int d = lane;
    const float* o_b = o_all + (long)b * LL * CC * DD;
    // u (seg 0)
    float uacc = 0.f;
#pragma unroll
    for (int lc = 0; lc < LL * CC; ++lc) uacc += o_b[lc * DD + d];
    float u_d = uacc * (1.f / CC);
    // ci (seg 1) and cn (seg 2)
    float res[2];
#pragma unroll
    for (int sgi = 1; sgi <= 2; ++sgi) {
        const float* o_c = o_all + ((long)sgi * NG + (long)b * LL * CC) * DD;
        const float* ie_buf = (sgi == 1) ? ie_i : ie_n;
        float cs[CC];
#pragma unroll
        for (int c = 0; c < CC; ++c) {
            float a = 0.f;
#pragma unroll
            for (int l = 0; l < LL; ++l) a += o_c[(l * CC + c) * DD + d];
            cs[c] = a;
        }
        float p[CC - 1];
        float mx2 = -1e30f;
        for (int c = 0; c < CC - 1; ++c) {
            float dd2 = cs[0] * cs[c + 1];
#pragma unroll
            for (int m = 32; m > 0; m >>= 1) dd2 += __shfl_xor(dd2, m, 64);
            p[c] = sigmoidf_(dd2);
            mx2 = fmaxf(mx2, p[c]);
        }
        float se2 = 0.f;
        for (int c = 0; c < CC - 1; ++c) {
            p[c] = __expf(p[c] - mx2);
            se2 += p[c];
        }
        float mcf = 0.f;
        for (int c = 0; c < CC - 1; ++c) mcf += (p[c] / se2) * cs[c + 1];
        float ie = ie_buf[b * DD + d];
        float ad = ie * mcf;
#pragma unroll
        for (int m = 32; m > 0; m >>= 1) ad += __shfl_xor(ad, m, 64);
        float alpha = sigmoidf_(ad);
        res[sgi - 1] = alpha / (1.f + alpha) * mcf + cs[0] + ie;
    }
    float sc1 = u_d * res[0];
    float sc2 = u_d * res[1];
#pragma unroll
    for (int m = 32; m > 0; m >>= 1) {
        sc1 += __shfl_xor(sc1, m, 64);
        sc2 += __shfl_xor(sc2, m, 64);
    }
    if (d == 0) {
        out[b] = sc1;
        out[BB + b] = sc2;
    }
}

extern "C" void kernel_launch(void* const* d_in, const int* in_sizes, int n_in,
                              void* d_out, int out_size, void* d_ws, size_t ws_size,
                              hipStream_t stream) {
    const int* ucv = (const int*)d_in[0];
    const int* items = (const int*)d_in[1];
    const int* negs = (const int*)d_in[2];
    const int* uts = (const int*)d_in[3];
    const int* its = (const int*)d_in[4];
    const int* nts = (const int*)d_in[5];
    const int* ucl = (const int*)d_in[6];
    const int* icl = (const int*)d_in[7];
    const int* ncl = (const int*)d_in[8];
    const float* E = (const float*)d_in[9];
    const float* R = (const float*)d_in[10];
    const float* W = (const float*)d_in[11];
    const float* W_ht = (const float*)d_in[12];
    const float* Wc = (const float*)d_in[13];
    const float* Wv = (const float*)d_in[14];

    float* ws = (float*)d_ws;
    float* wcce_u = ws;                   // B*128
    float* whv_u = wcce_u + BB * 128;     // B*128
    float* wcce_i = whv_u + BB * 128;     // B*128
    float* wcce_n = wcce_i + BB * 128;    // B*128
    float* ie_i = wcce_n + BB * 128;      // B*64
    float* ie_n = ie_i + BB * DD;         // B*64
    float* dots_r = ie_n + BB * DD;       // 3*B*32
    float* o_all = dots_r + 3 * BB * 32;  // 3*NG*64
    int* cnt = (int*)(o_all + 3L * NG * DD);             // B ints
    _Float16* E16 = (_Float16*)(cnt + BB);               // NE_ROWS*64 halves (25.6MB)

    pre_all<<<PRE_GRID, 256, 0, stream>>>(E, R, ucv, ucl, items, icl, negs, ncl, W, W_ht,
                                          Wc, Wv, wcce_u, whv_u, wcce_i, wcce_n, ie_i,
                                          ie_n, dots_r, E16, cnt);
    layer_all<<<3 * NG, 64, 0, stream>>>(E16, uts, its, nts, wcce_u, whv_u, wcce_i, wcce_n,
                                         dots_r, ie_i, ie_n, o_all, cnt, (float*)d_out);
}

// Round 16
// 56.394 us; speedup vs baseline: 10.1971x; 10.1971x over previous
//
#include <hip/hip_runtime.h>
#include <math.h>

#define BB 256
#define LL 3
#define CC 8
#define VV 20
#define SS 32
#define DD 64
#define NG (BB * LL * CC)  // 6144 groups per segment
#define NE_ROWS 200001
#define PRE_GRID 2048      // 256 prologue blocks + 1792 conv blocks

typedef float v4f __attribute__((ext_vector_type(4)));
typedef _Float16 h4 __attribute__((ext_vector_type(4)));

__device__ __forceinline__ float sigmoidf_(float x) { return 1.0f / (1.0f + __expf(-x)); }
__device__ __forceinline__ float dot4v_(v4f a, v4f b) {
    return a[0] * b[0] + a[1] * b[1] + a[2] * b[2] + a[3] * b[3];
}

// ---------------- K1: fused {prologue (blocks 0..255)} || {fp32->fp16 conv (rest)} ------
__global__ __launch_bounds__(256) void pre_all(
    const float* __restrict__ E, const float* __restrict__ Rr, const int* __restrict__ ucv,
    const int* __restrict__ ucl, const int* __restrict__ items, const int* __restrict__ icl,
    const int* __restrict__ negs, const int* __restrict__ ncl, const float* __restrict__ W,
    const float* __restrict__ W_ht, const float* __restrict__ Wc, const float* __restrict__ Wv,
    float* __restrict__ wcce_u, float* __restrict__ whv_u, float* __restrict__ wcce_i,
    float* __restrict__ wcce_n, float* __restrict__ ie_i, float* __restrict__ ie_n,
    float* __restrict__ dots_r, _Float16* __restrict__ E16) {
    int tid = threadIdx.x;
    if (blockIdx.x >= BB) {
        // ---- conversion lane: stream E (51MB) -> E16 (25.6MB), grid-stride ----
        int n4 = (NE_ROWS * DD) / 4;
        int nconv = (PRE_GRID - BB) * 256;
        for (int i = (blockIdx.x - BB) * 256 + tid; i < n4; i += nconv) {
            v4f x = *(const v4f*)(E + (long)i * 4);
            h4 o;
            o[0] = (_Float16)x[0];
            o[1] = (_Float16)x[1];
            o[2] = (_Float16)x[2];
            o[3] = (_Float16)x[3];
            *(h4*)(E16 + (long)i * 4) = o;
        }
        return;
    }
    // ---- prologue lane: per-b block ----
    int b = blockIdx.x;
    int d = tid & 63, q = tid >> 6;  // q in 0..3
    __shared__ float vcs[CC][DD];
    __shared__ float part[4][DD];
    __shared__ float part2[4][DD];
    __shared__ float cce_u_s[DD], vce_u_s[DD], cce_i_s[DD], cce_n_s[DD], vmean_s[DD];
    __shared__ float ie_s[2][DD];
    __shared__ float smw[3][DD];  // wc_r halves: [0]=user, [1]=item, [2]=neg

    float p1 = 0.f;
    for (int cc = 0; cc < 2; ++cc) {
        int c = q + cc * 4;
        const int* iv = ucv + (b * CC + c) * VV;
        float a = 0.f;
#pragma unroll
        for (int v = 0; v < VV; ++v) a += E[(long)iv[v] * DD + d];
        vcs[c][d] = a;
        p1 += E[(long)ucl[b * CC + c] * DD + d];
    }
    part[q][d] = p1;
    __syncthreads();
    {
        float sacc = 0.f;
        for (int cc = 0; cc < 2; ++cc) {
            int c = q + cc * 4;
            float m = 0.f;
#pragma unroll 8
            for (int k = 0; k < DD; ++k) m += vcs[c][k] * Wc[k * DD + d];
            sacc += sigmoidf_(m);
        }
        part2[q][d] = sacc;
    }
    __syncthreads();
    if (q == 0) {
        float s = 0.f;
#pragma unroll
        for (int i = 0; i < 4; ++i) s += part[i][d] + part2[i][d];
        cce_u_s[d] = s * (1.f / CC);
        float vm = 0.f;
#pragma unroll
        for (int c = 0; c < CC; ++c) vm += vcs[c][d];
        vmean_s[d] = vm * (1.f / CC);
    }
    __syncthreads();
    {
        float m = 0.f;
        for (int k = q * 16; k < q * 16 + 16; ++k) m += vmean_s[k] * Wv[k * DD + d];
        part[q][d] = m;
    }
    {
        const int* cl = (q < 2) ? icl : ncl;
        int c0 = (q & 1) ? 5 : 1, c1 = (q & 1) ? 8 : 5;
        float m = 0.f;
        for (int c = c0; c < c1; ++c) m += E[(long)cl[b * CC + c] * DD + d];
        part2[q][d] = m;
        if (q == 1) ie_s[0][d] = E[(long)items[b] * DD + d];
        if (q == 3) ie_s[1][d] = E[(long)negs[b] * DD + d];
    }
    __syncthreads();
    if (q == 0) {
        vce_u_s[d] = sigmoidf_(part[0][d] + part[1][d] + part[2][d] + part[3][d]);
        float ie = ie_s[0][d];
        cce_i_s[d] = ie * (1.f + (part2[0][d] + part2[1][d]) * (1.f / 7.f));
        ie_i[b * DD + d] = ie;
    } else if (q == 1) {
        float ie = ie_s[1][d];
        cce_n_s[d] = ie * (1.f + (part2[2][d] + part2[3][d]) * (1.f / 7.f));
        ie_n[b * DD + d] = ie;
    }
    __syncthreads();
    // Phase E: 4 mat-vecs; capture wc_r halves (k>=64) into smem for phase F
    {
        int k = tid & 127, sel = tid >> 7;
        const float* wr = (sel ? W_ht : W) + k * DD;
        const float* wr2 = W + k * DD;
        const float* v1 = sel ? vce_u_s : cce_u_s;
        const float* v2 = sel ? cce_n_s : cce_i_s;
        float a = 0.f, c2 = 0.f;
#pragma unroll 8
        for (int kk = 0; kk < DD; ++kk) {
            a += wr[kk] * v1[kk];
            c2 += wr2[kk] * v2[kk];
        }
        if (sel == 0) {
            wcce_u[b * 128 + k] = a;
            wcce_i[b * 128 + k] = c2;
            if (k >= 64) {
                smw[0][k - 64] = a;
                smw[1][k - 64] = c2;
            }
        } else {
            whv_u[b * 128 + k] = a;
            wcce_n[b * 128 + k] = c2;
            if (k >= 64) smw[2][k - 64] = c2;
        }
    }
    __syncthreads();
    // Phase F: dots_r[seg][b][rel] = R[rel] . wc_r[seg]  (96 len-64 dots; R is 8KB-hot)
    if (tid < 96) {
        int sg = tid >> 5, rel = tid & 31;
        const float* rr = Rr + rel * DD;
        float acc = 0.f;
#pragma unroll 8
        for (int k = 0; k < DD; ++k) acc += rr[k] * smw[sg][k];
        dots_r[(sg * BB + b) * 32 + rel] = acc;
    }
}

// ---------------- K2: layer_emb; 1-wave blocks, trickle loads, fp16 rows (1 line/row) --
__global__ __launch_bounds__(64) void layer_all(
    const _Float16* __restrict__ E16, const int* __restrict__ uts, const int* __restrict__ its,
    const int* __restrict__ nts, const float* __restrict__ wcce_u,
    const float* __restrict__ whv_u, const float* __restrict__ wcce_i,
    const float* __restrict__ wcce_n, const float* __restrict__ dots_r,
    float* __restrict__ o_all) {
    int lane = threadIdx.x;
    int f = lane & 15, grp = lane >> 4;  // 16 f-lanes x 4 row-groups
    int gg = blockIdx.x;
    int seg = gg / NG;
    int g = gg - seg * NG;
    int b = g / (LL * CC);
    const int* ts = (seg == 0) ? uts : (seg == 1) ? its : nts;
    const float* wcp = (seg == 0) ? wcce_u : (seg == 1) ? wcce_i : wcce_n;
    const bool has_p2 = (seg == 0);
    const int* tg = ts + (long)g * 3 * SS;

    // coalesced index loads + broadcast
    int idx_a = tg[lane];              // h: lanes 0..31, r: lanes 32..63
    int idx_b = tg[64 + (lane & 31)];  // t
    int hix[8], rixl[8], tix[8];
#pragma unroll
    for (int p = 0; p < 8; ++p) {
        int row = p * 4 + grp;
        hix[p] = __shfl(idx_a, row, 64);
        rixl[p] = __shfl(idx_a, 32 + row, 64);
        tix[p] = __shfl(idx_b, row, 64);
    }
    // r contribution via precomputed dot table (fp32-exact, L2-hot)
    const float* drb = dots_r + ((long)seg * BB + b) * 32;
    float rdot[8];
#pragma unroll
    for (int p = 0; p < 8; ++p) rdot[p] = drb[rixl[p]];
    v4f wch = ((const v4f*)(wcp + b * 128))[f];
    v4f whh = {0.f, 0.f, 0.f, 0.f}, wht = whh;
    if (has_p2) {
        whh = ((const v4f*)(whv_u + b * 128))[f];
        wht = ((const v4f*)(whv_u + b * 128))[16 + f];
    }
    // 16 row gathers from fp16 table: lane reads 8B (4 halves); 16 lanes = 1 cache line
    v4f hv[8], t4[8];
#pragma unroll
    for (int p = 0; p < 8; ++p) {
        h4 x = *(const h4*)(E16 + (long)hix[p] * DD + f * 4);
        hv[p] = (v4f){(float)x[0], (float)x[1], (float)x[2], (float)x[3]};
    }
#pragma unroll
    for (int p = 0; p < 8; ++p) {
        h4 x = *(const h4*)(E16 + (long)tix[p] * DD + f * 4);
        t4[p] = (v4f){(float)x[0], (float)x[1], (float)x[2], (float)x[3]};
    }

    float s1[8], s2[8];
#pragma unroll
    for (int p = 0; p < 8; ++p) {
        float a1 = dot4v_(hv[p], wch);
#pragma unroll
        for (int m = 1; m < 16; m <<= 1) a1 += __shfl_xor(a1, m, 64);
        s1[p] = a1 + rdot[p];
    }
    if (has_p2) {
#pragma unroll
        for (int p = 0; p < 8; ++p) {
            float a2 = dot4v_(hv[p], whh) + dot4v_(t4[p], wht);
#pragma unroll
            for (int m = 1; m < 16; m <<= 1) a2 += __shfl_xor(a2, m, 64);
            s2[p] = a2;
        }
    }
    // softmax over the 32 rows (8 per lane-column x 4 grps)
    float mx = -1e30f;
#pragma unroll
    for (int p = 0; p < 8; ++p) {
        s1[p] = sigmoidf_(s1[p]);
        mx = fmaxf(mx, s1[p]);
    }
    mx = fmaxf(mx, __shfl_xor(mx, 16, 64));
    mx = fmaxf(mx, __shfl_xor(mx, 32, 64));
    float se = 0.f;
#pragma unroll
    for (int p = 0; p < 8; ++p) {
        s1[p] = __expf(s1[p] - mx);
        se += s1[p];
    }
    se += __shfl_xor(se, 16, 64);
    se += __shfl_xor(se, 32, 64);
    float inv = 1.f / se;
    float4 oacc = make_float4(0.f, 0.f, 0.f, 0.f);
#pragma unroll
    for (int p = 0; p < 8; ++p) {
        float wgt = s1[p] * inv;
        if (has_p2) wgt *= sigmoidf_(s2[p]);
        oacc.x += wgt * t4[p][0];
        oacc.y += wgt * t4[p][1];
        oacc.z += wgt * t4[p][2];
        oacc.w += wgt * t4[p][3];
    }
#pragma unroll
    for (int m = 16; m <= 32; m <<= 1) {
        oacc.x += __shfl_xor(oacc.x, m, 64);
        oacc.y += __shfl_xor(oacc.y, m, 64);
        oacc.z += __shfl_xor(oacc.z, m, 64);
        oacc.w += __shfl_xor(oacc.w, m, 64);
    }
    float qq = oacc.x * oacc.x + oacc.y * oacc.y + oacc.z * oacc.z + oacc.w * oacc.w;
#pragma unroll
    for (int m = 1; m < 16; m <<= 1) qq += __shfl_xor(qq, m, 64);
    float innorm = 1.f / fmaxf(sqrtf(qq), 1e-12f);
    if (grp == 0) {
        oacc.x *= innorm;
        oacc.y *= innorm;
        oacc.z *= innorm;
        oacc.w *= innorm;
        *(float4*)(o_all + (long)gg * DD + f * 4) = oacc;
    }
}

// ---------------- K3: fused postlude (per-b block, 3 waves; o already normalized) -------
__global__ __launch_bounds__(192) void postlude(const float* __restrict__ o_all,
                                                const float* __restrict__ ie_i,
                                                const float* __restrict__ ie_n,
                                                float* __restrict__ out) {
    int b = blockIdx.x, tid = threadIdx.x;
    int w = tid / 64, d = tid & 63;
    __shared__ float u_s[DD], ci_s[DD], cn_s[DD];
    if (w == 0) {
        const float* o_u = o_all + (long)b * LL * CC * DD;
        float acc = 0.f;
#pragma unroll
        for (int lc = 0; lc < LL * CC; ++lc) acc += o_u[lc * DD + d];
        u_s[d] = acc * (1.f / CC);
    } else {
        const float* o_c = o_all + ((long)w * NG + (long)b * LL * CC) * DD;
        const float* ie_buf = (w == 1) ? ie_i : ie_n;
        float cs[CC];
#pragma unroll
        for (int c = 0; c < CC; ++c) {
            float a = 0.f;
#pragma unroll
            for (int l = 0; l < LL; ++l) a += o_c[(l * CC + c) * DD + d];
            cs[c] = a;
        }
        float p[CC - 1];
        float mx = -1e30f;
        for (int c = 0; c < CC - 1; ++c) {
            float dd2 = cs[0] * cs[c + 1];
#pragma unroll
            for (int m = 32; m > 0; m >>= 1) dd2 += __shfl_xor(dd2, m, 64);
            p[c] = sigmoidf_(dd2);
            mx = fmaxf(mx, p[c]);
        }
        float se = 0.f;
        for (int c = 0; c < CC - 1; ++c) {
            p[c] = __expf(p[c] - mx);
            se += p[c];
        }
        float mcf = 0.f;
        for (int c = 0; c < CC - 1; ++c) mcf += (p[c] / se) * cs[c + 1];
        float ie = ie_buf[b * DD + d];
        float ad = ie * mcf;
#pragma unroll
        for (int m = 32; m > 0; m >>= 1) ad += __shfl_xor(ad, m, 64);
        float alpha = sigmoidf_(ad);
        float res = alpha / (1.f + alpha) * mcf + cs[0] + ie;
        if (w == 1)
            ci_s[d] = res;
        else
            cn_s[d] = res;
    }
    __syncthreads();
    if (w == 0) {
        float uv = u_s[d];
        float s1 = uv * ci_s[d];
        float s2 = uv * cn_s[d];
#pragma unroll
        for (int m = 32; m > 0; m >>= 1) {
            s1 += __shfl_xor(s1, m, 64);
            s2 += __shfl_xor(s2, m, 64);
        }
        if (d == 0) {
            out[b] = s1;
            out[BB + b] = s2;
        }
    }
}

extern "C" void kernel_launch(void* const* d_in, const int* in_sizes, int n_in,
                              void* d_out, int out_size, void* d_ws, size_t ws_size,
                              hipStream_t stream) {
    const int* ucv = (const int*)d_in[0];
    const int* items = (const int*)d_in[1];
    const int* negs = (const int*)d_in[2];
    const int* uts = (const int*)d_in[3];
    const int* its = (const int*)d_in[4];
    const int* nts = (const int*)d_in[5];
    const int* ucl = (const int*)d_in[6];
    const int* icl = (const int*)d_in[7];
    const int* ncl = (const int*)d_in[8];
    const float* E = (const float*)d_in[9];
    const float* R = (const float*)d_in[10];
    const float* W = (const float*)d_in[11];
    const float* W_ht = (const float*)d_in[12];
    const float* Wc = (const float*)d_in[13];
    const float* Wv = (const float*)d_in[14];

    float* ws = (float*)d_ws;
    float* wcce_u = ws;                   // B*128
    float* whv_u = wcce_u + BB * 128;     // B*128
    float* wcce_i = whv_u + BB * 128;     // B*128
    float* wcce_n = wcce_i + BB * 128;    // B*128
    float* ie_i = wcce_n + BB * 128;      // B*64
    float* ie_n = ie_i + BB * DD;         // B*64
    float* dots_r = ie_n + BB * DD;       // 3*B*32
    float* o_all = dots_r + 3 * BB * 32;  // 3*NG*64
    _Float16* E16 = (_Float16*)(o_all + 3L * NG * DD);  // NE_ROWS*64 halves (25.6MB)

    pre_all<<<PRE_GRID, 256, 0, stream>>>(E, R, ucv, ucl, items, icl, negs, ncl, W, W_ht,
                                          Wc, Wv, wcce_u, whv_u, wcce_i, wcce_n, ie_i,
                                          ie_n, dots_r, E16);
    layer_all<<<3 * NG, 64, 0, stream>>>(E16, uts, its, nts, wcce_u, whv_u, wcce_i, wcce_n,
                                         dots_r, o_all);
    postlude<<<BB, 192, 0, stream>>>(o_all, ie_i, ie_n, (float*)d_out);
}